// Round 1
// 107.869 us; speedup vs baseline: 1.0540x; 1.0540x over previous
//
#include <hip/hip_runtime.h>

// B=32, C=64, S=64, J=4, m=4, experts 6.  Gates: g_e=lam[e] (e<4), g4=lam4+lam6,
// g5=lam5+lam7, G=sum(lam).  out = G*x + (1/16)*sum_band sigma_band * Delta_band.
//
// ws layout (floats):
//   coef   : [band4][X4][Y4][b32][c64]                 131072 f (512 KB)
//   delta  : [q4][band4][X4][Y4][b32][c64] partials    524288 f (2 MB)
//   wpack2 : [bxy=band*16+xy][eg=ei/4][o64][er=ei%4]   1572864 f (6 MB)
//
// R3: kB split 4x along the eg reduction axis (256 blocks, full-GPU mix);
// kC sums the 4 partial delta slabs.  Rest identical to R2 (113.7us).

#define COEF_N 131072
#define DELTA_N (4 * COEF_N)

typedef float floatx4 __attribute__((ext_vector_type(4)));

// ---------------- Kernel A: analysis (blocks 0..511) + weight repack (512..895) ----
__global__ __launch_bounds__(256) void kA(const float* __restrict__ x,
                                          const float* __restrict__ WL,
                                          const float* __restrict__ WH,
                                          float* __restrict__ coef,
                                          float* __restrict__ wpack2) {
  int bi = blockIdx.x;
  int tid = threadIdx.x;
  if (bi < 512) {
    // 4-level Haar coarse coefficients = signed 16x16 block sums / 16, via float4
    int b = bi >> 4;            // batch
    int cg = bi & 15;
    int wave = tid >> 6;
    int lane = tid & 63;
    int c = cg * 4 + wave;      // channel
    const float4* img4 = (const float4*)(x + (size_t)(b * 64 + c) * 4096);
    int col4 = lane & 15;       // float4 column (cols 4*col4..4*col4+3)
    int rgrp = lane >> 4;       // row offset 0..3
    float top[4] = {0.f, 0.f, 0.f, 0.f}, bot[4] = {0.f, 0.f, 0.f, 0.f};
#pragma unroll
    for (int t = 0; t < 16; ++t) {
      int row = t * 4 + rgrp;
      float4 v = img4[row * 16 + col4];
      float s = v.x + v.y + v.z + v.w;          // same sign region horizontally
      if ((t & 3) < 2) top[t >> 2] += s;         // row&15 < 8
      else             bot[t >> 2] += s;
    }
    float sc = ((col4 & 3) < 2) ? 1.0f : -1.0f;  // + left 8 cols of 16-block
    int Y = col4 >> 2;
#pragma unroll
    for (int X = 0; X < 4; ++X) {
      float s = top[X] + bot[X];
      float d = top[X] - bot[X];
      float r[4];
      r[0] = s; r[1] = d; r[2] = sc * s; r[3] = sc * d;  // LL, LH, HL, HH
#pragma unroll
      for (int band = 0; band < 4; ++band) {
        float v = r[band];
        v += __shfl_xor(v, 1, 64);    // col-lane bits
        v += __shfl_xor(v, 2, 64);
        v += __shfl_xor(v, 16, 64);   // row-lane bits
        v += __shfl_xor(v, 32, 64);
        if ((lane & 3) == 0 && rgrp == 0) {
          coef[(((band * 4 + X) * 4 + Y) * 32 + b) * 64 + c] = v * 0.0625f;
        }
      }
    }
  } else {
    // repack: wpack2[bxy][ei/4][o][ei%4] = W[e,(band),i,o,xy]
    int gid = (bi - 512) * 256 + tid;   // [0, 98304)
    int o = gid & 63;
    int i = (gid >> 6) & 63;
    int be = gid >> 12;                  // 0..23
    int e = be % 6;
    int band = be / 6;
    const float* src;
    if (band == 0) src = WL + (size_t)((e * 64 + i) * 64 + o) * 16;
    else           src = WH + (size_t)(((e * 3 + (band - 1)) * 64 + i) * 64 + o) * 16;
    const float4* s4 = (const float4*)src;
    float4 v0 = s4[0], v1 = s4[1], v2 = s4[2], v3 = s4[3];
    float vv[16] = {v0.x, v0.y, v0.z, v0.w, v1.x, v1.y, v1.z, v1.w,
                    v2.x, v2.y, v2.z, v2.w, v3.x, v3.y, v3.z, v3.w};
    int ei = e * 64 + i;
    int eg = ei >> 2, er = ei & 3;
#pragma unroll
    for (int xy = 0; xy < 16; ++xy) {
      int bxy = band * 16 + xy;
      wpack2[(((size_t)bxy * 96 + eg) * 64 + o) * 4 + er] = vv[xy];
    }
  }
}

// ---------------- Kernel B: per-(band,xy,q) partial mix ---------------------------
// block = (bxy, q): q-th quarter of the ei reduction (eg 24q..24q+23).
// delta[q][bxy][b][o] = sum_{ei in quarter} g*A*W  (- G*A[b,o] folded into q==0)
__global__ __launch_bounds__(512) void kB(const float* __restrict__ coef,
                                          const float* __restrict__ wpack2,
                                          const float* __restrict__ lam,
                                          float* __restrict__ delta) {
  __shared__ float4 Agv[96][8];    // [ei_local][bq]: gated A for b=4bq..4bq+3 (12 KB)
  __shared__ float rawA[32][65];   // [b][i] (+1 pad)
  __shared__ float gg[32][8];      // g0..g5, G
  int blk = blockIdx.x;
  int bxy = blk >> 2;
  int q = blk & 3;
  int tid = threadIdx.x;
  const float* cslab = coef + (size_t)bxy * 2048;
  for (int idx = tid; idx < 2048; idx += 512) rawA[idx >> 6][idx & 63] = cslab[idx];
  if (tid < 32) {
    int b = tid;
    float l[8];
#pragma unroll
    for (int j = 0; j < 8; ++j) l[j] = lam[b * 8 + j];
    gg[b][0] = l[0]; gg[b][1] = l[1]; gg[b][2] = l[2]; gg[b][3] = l[3];
    gg[b][4] = l[4] + l[6];
    gg[b][5] = l[5] + l[7];
    gg[b][6] = l[0] + l[1] + l[2] + l[3] + l[4] + l[5] + l[6] + l[7];
  }
  __syncthreads();
  for (int idx = tid; idx < 96 * 8; idx += 512) {
    int eil = idx >> 3, bq = idx & 7;
    int ei = q * 96 + eil;
    int e = ei >> 6, i = ei & 63;
    float4 a;
    a.x = gg[bq * 4 + 0][e] * rawA[bq * 4 + 0][i];
    a.y = gg[bq * 4 + 1][e] * rawA[bq * 4 + 1][i];
    a.z = gg[bq * 4 + 2][e] * rawA[bq * 4 + 2][i];
    a.w = gg[bq * 4 + 3][e] * rawA[bq * 4 + 3][i];
    Agv[eil][bq] = a;
  }
  __syncthreads();
  int o = tid & 63;
  int bq = tid >> 6;               // wave-uniform
  const float4* wp = (const float4*)wpack2 + (size_t)bxy * (96 * 64) +
                     (size_t)(q * 24) * 64 + o;
  float acc0 = 0.f, acc1 = 0.f, acc2 = 0.f, acc3 = 0.f;
  for (int eg = 0; eg < 24; ++eg) {
    float4 w = wp[(size_t)eg * 64];          // weights for ei=q*96+4eg.. at this o
    float4 a0 = Agv[eg * 4 + 0][bq];         // broadcast ds_read_b128
    float4 a1 = Agv[eg * 4 + 1][bq];
    float4 a2 = Agv[eg * 4 + 2][bq];
    float4 a3 = Agv[eg * 4 + 3][bq];
    acc0 += a0.x * w.x + a1.x * w.y + a2.x * w.z + a3.x * w.w;
    acc1 += a0.y * w.x + a1.y * w.y + a2.y * w.z + a3.y * w.w;
    acc2 += a0.z * w.x + a1.z * w.y + a2.z * w.z + a3.z * w.w;
    acc3 += a0.w * w.x + a1.w * w.y + a2.w * w.z + a3.w * w.w;
  }
  float* dslab = delta + (size_t)(q * 64 + bxy) * 2048;
  if (q == 0) {
    float G0 = gg[bq * 4 + 0][6], G1 = gg[bq * 4 + 1][6];
    float G2 = gg[bq * 4 + 2][6], G3 = gg[bq * 4 + 3][6];
    dslab[(bq * 4 + 0) * 64 + o] = acc0 - G0 * rawA[bq * 4 + 0][o];
    dslab[(bq * 4 + 1) * 64 + o] = acc1 - G1 * rawA[bq * 4 + 1][o];
    dslab[(bq * 4 + 2) * 64 + o] = acc2 - G2 * rawA[bq * 4 + 2][o];
    dslab[(bq * 4 + 3) * 64 + o] = acc3 - G3 * rawA[bq * 4 + 3][o];
  } else {
    dslab[(bq * 4 + 0) * 64 + o] = acc0;
    dslab[(bq * 4 + 1) * 64 + o] = acc1;
    dslab[(bq * 4 + 2) * 64 + o] = acc2;
    dslab[(bq * 4 + 3) * 64 + o] = acc3;
  }
}

// ---------------- Kernel C: out = G·x + (1/16)(ΔLL + σr ΔLH + σc ΔHL + σrσc ΔHH) ---
__global__ __launch_bounds__(256) void kC(const float* __restrict__ x,
                                          const float* __restrict__ delta,
                                          const float* __restrict__ lam,
                                          float* __restrict__ out) {
  int bo = blockIdx.x;             // b*64 + o
  int b = bo >> 6, o = bo & 63;
  int tid = threadIdx.x;
  __shared__ float ds[64];         // [band*16 + X*4 + Y]
  if (tid < 64) {
    int band = tid >> 4, xy = tid & 15;
    float s = 0.f;
#pragma unroll
    for (int q = 0; q < 4; ++q) {
      s += delta[((size_t)(q * 64 + band * 16 + xy) * 32 + b) * 64 + o];
    }
    ds[tid] = s;
  }
  __syncthreads();
  float G = 0.f;
#pragma unroll
  for (int j = 0; j < 8; ++j) G += lam[b * 8 + j];
  int w4 = tid & 15;               // float4 column index
  int h0 = tid >> 4;               // row within 16-block
  int Y = w4 >> 2;
  float sc = ((w4 & 3) < 2) ? 1.f : -1.f;
  float sr = (h0 < 8) ? 1.f : -1.f;
  const float4* xi = (const float4*)(x + (size_t)bo * 4096);
  floatx4* oi = (floatx4*)(out + (size_t)bo * 4096);
#pragma unroll
  for (int X = 0; X < 4; ++X) {
    float dsel = (ds[X * 4 + Y] + sr * ds[16 + X * 4 + Y] +
                  sc * ds[32 + X * 4 + Y] + sr * sc * ds[48 + X * 4 + Y]) * 0.0625f;
    int idx = (X * 16 + h0) * 16 + w4;
    float4 v = xi[idx];
    floatx4 r;
    r.x = G * v.x + dsel;
    r.y = G * v.y + dsel;
    r.z = G * v.z + dsel;
    r.w = G * v.w + dsel;
    // write-only output stream: nontemporal store avoids RFO/L2 pollution
    __builtin_nontemporal_store(r, &oi[idx]);
  }
}

extern "C" void kernel_launch(void* const* d_in, const int* in_sizes, int n_in,
                              void* d_out, int out_size, void* d_ws, size_t ws_size,
                              hipStream_t stream) {
  const float* x   = (const float*)d_in[0];
  const float* lam = (const float*)d_in[1];
  const float* WL  = (const float*)d_in[2];
  const float* WH  = (const float*)d_in[3];
  float* out = (float*)d_out;
  float* coef   = (float*)d_ws;
  float* delta  = coef + COEF_N;
  float* wpack2 = delta + DELTA_N;

  hipLaunchKernelGGL(kA, dim3(896), dim3(256), 0, stream, x, WL, WH, coef, wpack2);
  hipLaunchKernelGGL(kB, dim3(256), dim3(512), 0, stream, coef, wpack2, lam, delta);
  hipLaunchKernelGGL(kC, dim3(2048), dim3(256), 0, stream, x, delta, lam, out);
}